// Round 2
// baseline (548.608 us; speedup 1.0000x reference)
//
#include <hip/hip_runtime.h>
#include <hip/hip_bf16.h>
#include <math.h>

#define B_N 16384
#define D_K 256

typedef __bf16 bf16x8 __attribute__((ext_vector_type(8)));
typedef float f32x16 __attribute__((ext_vector_type(16)));

__device__ __forceinline__ unsigned short f2bf(float x) {
  unsigned u = __float_as_uint(x);
  unsigned r = (u + 0x7fffu + ((u >> 16) & 1u)) >> 16;
  return (unsigned short)r;
}

__device__ __forceinline__ float fexp2(float x) {
#if __has_builtin(__builtin_amdgcn_exp2f)
  return __builtin_amdgcn_exp2f(x);
#else
  return exp2f(x);
#endif
}

// ---------------------------------------------------------------------------
// 1) fp32 -> bf16 conversion. z_seal copy is pre-scaled by scale*log2(e) so
//    the MFMA output is directly the exp2 argument.
// ---------------------------------------------------------------------------
__global__ void convert_kernel(const float* __restrict__ A, const float* __restrict__ Bm,
                               const float* __restrict__ lsp,
                               unsigned short* __restrict__ Abf,
                               unsigned short* __restrict__ Bbf) {
  const float c = fminf(expf(lsp[0]), 100.0f) * 1.4426950408889634f;
  int idx = (blockIdx.x * blockDim.x + threadIdx.x) * 4;  // exact: 4096*256*4 = 16384*256
  float4 a = *(const float4*)(A + idx);
  float4 b = *(const float4*)(Bm + idx);
  ushort4 ua, ub;
  ua.x = f2bf(a.x); ua.y = f2bf(a.y); ua.z = f2bf(a.z); ua.w = f2bf(a.w);
  ub.x = f2bf(b.x * c); ub.y = f2bf(b.y * c); ub.z = f2bf(b.z * c); ub.w = f2bf(b.w * c);
  *(ushort4*)(Abf + idx) = ua;
  *(ushort4*)(Bbf + idx) = ub;
}

// ---------------------------------------------------------------------------
// 2) diag[i] = <z_schema[i], z_seal[i]> in exact fp32 (unscaled)
// ---------------------------------------------------------------------------
__global__ void diag_kernel(const float* __restrict__ A, const float* __restrict__ Bm,
                            float* __restrict__ diag) {
  int w = threadIdx.x >> 6, l = threadIdx.x & 63;
  int row = blockIdx.x * 4 + w;
  const float4* a = (const float4*)(A + row * D_K);
  const float4* b = (const float4*)(Bm + row * D_K);
  float4 av = a[l], bv = b[l];
  float s = av.x * bv.x + av.y * bv.y + av.z * bv.z + av.w * bv.w;
#pragma unroll
  for (int off = 32; off; off >>= 1) s += __shfl_xor(s, off);
  if (l == 0) diag[row] = s;
}

// ---------------------------------------------------------------------------
// 3) Fused GEMM + online logsumexp.
//    dir 0: lse over rows of  scale*A.B^T  (X=A rows, Y=B stream)
//    dir 1: lse over rows of  scale*B.A^T  (X=B rows, Y=A stream) == col lse
//    Swapped MFMA: D = mfma(Y_frag, X_frag) -> D[j_local][i_local];
//    i_local = lane&31 (fixed per lane), 16 j values per lane -> row stats
//    are lane-local.
// ---------------------------------------------------------------------------
__device__ __forceinline__ void upd(float& m, float& s, const f32x16& a) {
  float t = a[0];
#pragma unroll
  for (int r = 1; r < 16; ++r) t = fmaxf(t, a[r]);
  float mn = fmaxf(m, t);
  s *= fexp2(m - mn);
  float p = 0.f;
#pragma unroll
  for (int r = 0; r < 16; ++r) p += fexp2(a[r] - mn);
  s += p;
  m = mn;
}

__global__ __launch_bounds__(256, 2) void lse_kernel(const unsigned short* __restrict__ Abf,
                                                     const unsigned short* __restrict__ Bbf,
                                                     float* __restrict__ lse_out) {
  const int bid = blockIdx.x;
  const int dir = bid >> 8;
  const int blk = bid & 255;
  const unsigned short* X = dir ? Bbf : Abf;
  const unsigned short* Y = dir ? Abf : Bbf;
  const int i0 = blk * 64;
  const int w = threadIdx.x >> 6;
  const int l = threadIdx.x & 63;
  const int lc = l & 31, lh = l >> 5;

  // X fragments: 64 rows x 256 k in registers (128 VGPR)
  bf16x8 xf[2][16];
#pragma unroll
  for (int it = 0; it < 2; ++it)
#pragma unroll
    for (int kk = 0; kk < 16; ++kk)
      xf[it][kk] = *(const bf16x8*)(X + (i0 + it * 32 + lc) * D_K + kk * 16 + lh * 8);

  float m0 = -INFINITY, s0 = 0.f, m1 = -INFINITY, s1 = 0.f;
  const unsigned short* Yw = Y + (w * 4096 + lc) * D_K + lh * 8;

  for (int jt = 0; jt < 128; ++jt) {
    const unsigned short* yrow = Yw + jt * 32 * D_K;
    f32x16 acc0 = {};
    f32x16 acc1 = {};
#pragma unroll
    for (int kk = 0; kk < 16; ++kk) {
      bf16x8 y = *(const bf16x8*)(yrow + kk * 16);
      acc0 = __builtin_amdgcn_mfma_f32_32x32x16_bf16(y, xf[0][kk], acc0, 0, 0, 0);
      acc1 = __builtin_amdgcn_mfma_f32_32x32x16_bf16(y, xf[1][kk], acc1, 0, 0, 0);
    }
    upd(m0, s0, acc0);
    upd(m1, s1, acc1);
  }

  // combine lane l with l^32 (same i, disjoint j sets)
  {
    float mo = __shfl_xor(m0, 32), so = __shfl_xor(s0, 32);
    float mn = fmaxf(m0, mo);
    s0 = s0 * fexp2(m0 - mn) + so * fexp2(mo - mn);
    m0 = mn;
    mo = __shfl_xor(m1, 32); so = __shfl_xor(s1, 32);
    mn = fmaxf(m1, mo);
    s1 = s1 * fexp2(m1 - mn) + so * fexp2(mo - mn);
    m1 = mn;
  }

  // cross-wave combine (each wave covered a disjoint j range)
  __shared__ float red[4][2][32][2];
  if (lh == 0) {
    red[w][0][lc][0] = m0; red[w][0][lc][1] = s0;
    red[w][1][lc][0] = m1; red[w][1][lc][1] = s1;
  }
  __syncthreads();
  if (threadIdx.x < 64) {
    int it = threadIdx.x >> 5, col = threadIdx.x & 31;
    float m = red[0][it][col][0], s = red[0][it][col][1];
#pragma unroll
    for (int ww = 1; ww < 4; ++ww) {
      float mo = red[ww][it][col][0], so = red[ww][it][col][1];
      float mn = fmaxf(m, mo);
      s = s * fexp2(m - mn) + so * fexp2(mo - mn);
      m = mn;
    }
    // logits were pre-scaled by scale*log2(e); convert lse back to natural
    float lse = 0.6931471805599453f * (m + log2f(s));
    lse_out[dir * B_N + i0 + it * 32 + col] = lse;
  }
}

// ---------------------------------------------------------------------------
// 4) final: loss = mean( 0.5*(lse_r+lse_c) - scale*diag )
// ---------------------------------------------------------------------------
__global__ void final_kernel(const float* __restrict__ lse, const float* __restrict__ diag,
                             const float* __restrict__ lsp, float* __restrict__ out) {
  const float scale = fminf(expf(lsp[0]), 100.0f);
  float part = 0.f;
  for (int i = threadIdx.x; i < B_N; i += 1024)
    part += 0.5f * (lse[i] + lse[B_N + i]) - scale * diag[i];
  __shared__ float red[1024];
  red[threadIdx.x] = part;
  __syncthreads();
  for (int off = 512; off; off >>= 1) {
    if (threadIdx.x < off) red[threadIdx.x] += red[threadIdx.x + off];
    __syncthreads();
  }
  if (threadIdx.x == 0) {
    float loss = red[0] / (float)B_N;
    out[0] = loss;
    out[1] = loss;
  }
}

extern "C" void kernel_launch(void* const* d_in, const int* in_sizes, int n_in,
                              void* d_out, int out_size, void* d_ws, size_t ws_size,
                              hipStream_t stream) {
  const float* A  = (const float*)d_in[0];  // z_schema
  const float* Bm = (const float*)d_in[1];  // z_seal
  const float* ls = (const float*)d_in[2];  // logit_scale
  float* out = (float*)d_out;

  char* ws = (char*)d_ws;
  unsigned short* Abf = (unsigned short*)ws;                       // 8 MB
  unsigned short* Bbf = Abf + (size_t)B_N * D_K;                   // 8 MB
  float* diagp = (float*)(ws + 2ull * B_N * D_K * 2);              // 64 KB
  float* lsep = diagp + B_N;                                       // 128 KB

  convert_kernel<<<4096, 256, 0, stream>>>(A, Bm, ls, Abf, Bbf);
  diag_kernel<<<4096, 256, 0, stream>>>(A, Bm, diagp);
  lse_kernel<<<512, 256, 0, stream>>>(Abf, Bbf, lsep);
  final_kernel<<<1, 1024, 0, stream>>>(lsep, diagp, ls, out);
}

// Round 3
// 332.626 us; speedup vs baseline: 1.6493x; 1.6493x over previous
//
#include <hip/hip_runtime.h>
#include <hip/hip_bf16.h>
#include <math.h>

#define B_N 16384
#define D_K 256
#define JS 8
#define JRANGE (B_N / JS)          // 2048 j-rows per block
#define TJ 32                      // j-rows per LDS tile
#define NT (JRANGE / TJ)           // 64 tiles
#define TILE_BYTES (TJ * D_K * 2)  // 16 KB

typedef __bf16 bf16x8 __attribute__((ext_vector_type(8)));
typedef float f32x16 __attribute__((ext_vector_type(16)));

__device__ __forceinline__ unsigned short f2bf(float x) {
  unsigned u = __float_as_uint(x);
  unsigned r = (u + 0x7fffu + ((u >> 16) & 1u)) >> 16;
  return (unsigned short)r;
}

__device__ __forceinline__ float fexp2(float x) {
#if __has_builtin(__builtin_amdgcn_exp2f)
  return __builtin_amdgcn_exp2f(x);
#else
  return exp2f(x);
#endif
}

__device__ __forceinline__ void load_lds16(const void* g, void* l) {
  __builtin_amdgcn_global_load_lds(
      (const __attribute__((address_space(1))) unsigned int*)g,
      (__attribute__((address_space(3))) unsigned int*)l, 16, 0, 0);
}

// ---------------------------------------------------------------------------
// 1) fp32 -> bf16; z_seal copy pre-scaled by scale*log2(e)
// ---------------------------------------------------------------------------
__global__ void convert_kernel(const float* __restrict__ A, const float* __restrict__ Bm,
                               const float* __restrict__ lsp,
                               unsigned short* __restrict__ Abf,
                               unsigned short* __restrict__ Bbf) {
  const float c = fminf(expf(lsp[0]), 100.0f) * 1.4426950408889634f;
  int idx = (blockIdx.x * blockDim.x + threadIdx.x) * 4;
  float4 a = *(const float4*)(A + idx);
  float4 b = *(const float4*)(Bm + idx);
  ushort4 ua, ub;
  ua.x = f2bf(a.x); ua.y = f2bf(a.y); ua.z = f2bf(a.z); ua.w = f2bf(a.w);
  ub.x = f2bf(b.x * c); ub.y = f2bf(b.y * c); ub.z = f2bf(b.z * c); ub.w = f2bf(b.w * c);
  *(ushort4*)(Abf + idx) = ua;
  *(ushort4*)(Bbf + idx) = ub;
}

// ---------------------------------------------------------------------------
// 2) diag[i] = <z_schema[i], z_seal[i]> exact fp32
// ---------------------------------------------------------------------------
__global__ void diag_kernel(const float* __restrict__ A, const float* __restrict__ Bm,
                            float* __restrict__ diag) {
  int w = threadIdx.x >> 6, l = threadIdx.x & 63;
  int row = blockIdx.x * 4 + w;
  const float4* a = (const float4*)(A + row * D_K);
  const float4* b = (const float4*)(Bm + row * D_K);
  float4 av = a[l], bv = b[l];
  float s = av.x * bv.x + av.y * bv.y + av.z * bv.z + av.w * bv.w;
#pragma unroll
  for (int off = 32; off; off >>= 1) s += __shfl_xor(s, off);
  if (l == 0) diag[row] = s;
}

// ---------------------------------------------------------------------------
// 3) Fused GEMM + online logsumexp, LDS-shared Y stream.
//    Block: 256 i-rows (wave w owns 64 in registers) x JRANGE j.
//    Y tile (32 j x 256 k bf16 = 16 KB) double-buffered in LDS via
//    global_load_lds, XOR-swizzled (granule slot ^= row&7) on BOTH the
//    pre-swizzled global source and the ds_read side (rule #21).
//    Swapped MFMA: D = mfma(Y, X) -> reduction axis j is lane-local.
// ---------------------------------------------------------------------------
__device__ __forceinline__ void upd(float& m, float& s, const f32x16& a) {
  float t = a[0];
#pragma unroll
  for (int r = 1; r < 16; ++r) t = fmaxf(t, a[r]);
  float mn = fmaxf(m, t);
  s *= fexp2(m - mn);
  float p = 0.f;
#pragma unroll
  for (int r = 0; r < 16; ++r) p += fexp2(a[r] - mn);
  s += p;
  m = mn;
}

__global__ __launch_bounds__(256, 2) void lse_kernel(const unsigned short* __restrict__ Abf,
                                                     const unsigned short* __restrict__ Bbf,
                                                     float* __restrict__ pm,
                                                     float* __restrict__ ps) {
  __shared__ __align__(16) unsigned char lds[2][TILE_BYTES];
  const int bid = blockIdx.x;
  const int dir = bid >> 9;            // 0/1
  const int iblk = (bid >> 3) & 63;    // 64 i-blocks
  const int js = bid & 7;              // low bits -> same js pinned per XCD
  const unsigned short* X = dir ? Bbf : Abf;
  const unsigned short* Y = dir ? Abf : Bbf;
  const int i0 = iblk * 256;
  const int j0 = js * JRANGE;
  const int w = threadIdx.x >> 6;
  const int l = threadIdx.x & 63;
  const int lc = l & 31, lh = l >> 5;

  // X fragments: this wave's 64 rows x 256 k (128 VGPR)
  bf16x8 xf0[16], xf1[16];
  {
    const unsigned short* Xr0 = X + (size_t)(i0 + w * 64 + lc) * D_K + lh * 8;
    const unsigned short* Xr1 = Xr0 + 32 * D_K;
#pragma unroll
    for (int kk = 0; kk < 16; ++kk) {
      xf0[kk] = *(const bf16x8*)(Xr0 + kk * 16);
      xf1[kk] = *(const bf16x8*)(Xr1 + kk * 16);
    }
  }

  float m0 = -INFINITY, s0 = 0.f, m1 = -INFINITY, s1 = 0.f;

  // STAGE(buf, t): stage Y rows [j0+t*32 .. +31] into lds[buf].
  // Thread granule G = w*256 + r*64 + l -> LDS row = G>>5 = w*8+2r+lh,
  // slot = lc. Content must be global granule (row, lc ^ (row&7)).
  // LDS dest is wave-uniform base + lane*16 (linear); source pre-swizzled.
#define STAGE(bufidx, t)                                                        \
  {                                                                             \
    _Pragma("unroll") for (int r = 0; r < 4; ++r) {                             \
      const int row = w * 8 + 2 * r + lh;                                       \
      const unsigned short* src =                                               \
          Y + (size_t)(j0 + (t) * TJ + row) * D_K + ((lc ^ (2 * r + lh)) << 3); \
      load_lds16(src, &lds[bufidx][w * 4096 + r * 1024]);                       \
    }                                                                           \
  }

  // CONSUME(buf): 16 swizzled ds_read_b128 + 32 MFMA + online-softmax update.
  // Read logical (row=lc, granule g=2kk+lh) at phys slot g ^ (lc&7).
#define CONSUME(bufidx)                                                           \
  {                                                                              \
    f32x16 acc0 = {};                                                            \
    f32x16 acc1 = {};                                                            \
    _Pragma("unroll") for (int kk = 0; kk < 16; ++kk) {                          \
      bf16x8 y = *(const bf16x8*)(                                               \
          &lds[bufidx][lc * 512 + ((((kk << 1) | lh) ^ (lc & 7)) << 4)]);        \
      acc0 = __builtin_amdgcn_mfma_f32_32x32x16_bf16(y, xf0[kk], acc0, 0, 0, 0); \
      acc1 = __builtin_amdgcn_mfma_f32_32x32x16_bf16(y, xf1[kk], acc1, 0, 0, 0); \
    }                                                                            \
    upd(m0, s0, acc0);                                                           \
    upd(m1, s1, acc1);                                                           \
  }

  STAGE(0, 0);
  for (int t = 0; t < NT; t += 2) {
    __syncthreads();                   // drains vmcnt -> buf0 ready
    if (t + 1 < NT) STAGE(1, t + 1);   // prefetch next while computing
    CONSUME(0);
    __syncthreads();                   // buf1 ready; all done reading buf0
    if (t + 2 < NT) STAGE(0, t + 2);
    CONSUME(1);
  }
#undef STAGE
#undef CONSUME

  // combine lane l with l^32 (same i, disjoint j_local subsets)
  {
    float mo = __shfl_xor(m0, 32), so = __shfl_xor(s0, 32);
    float mn = fmaxf(m0, mo);
    s0 = s0 * fexp2(m0 - mn) + so * fexp2(mo - mn); m0 = mn;
    mo = __shfl_xor(m1, 32); so = __shfl_xor(s1, 32);
    mn = fmaxf(m1, mo);
    s1 = s1 * fexp2(m1 - mn) + so * fexp2(mo - mn); m1 = mn;
  }

  // per-wave rows are complete over this block's j-range: write partials
  if (lh == 0) {
    const int base = js * (2 * B_N) + dir * B_N + i0 + w * 64 + lc;
    pm[base] = m0;      ps[base] = s0;
    pm[base + 32] = m1; ps[base + 32] = s1;
  }
}

// ---------------------------------------------------------------------------
// 4) combine JS partials per (dir,i) -> lse (natural log)
// ---------------------------------------------------------------------------
__global__ void combine_kernel(const float* __restrict__ pm, const float* __restrict__ ps,
                               float* __restrict__ lse) {
  int id = blockIdx.x * 256 + threadIdx.x;  // dir*B_N + i
  float m = -INFINITY, s = 0.f;
#pragma unroll
  for (int p = 0; p < JS; ++p) {
    float mo = pm[p * (2 * B_N) + id], so = ps[p * (2 * B_N) + id];
    float mn = fmaxf(m, mo);
    s = s * fexp2(m - mn) + so * fexp2(mo - mn);
    m = mn;
  }
  lse[id] = 0.6931471805599453f * (m + log2f(s));
}

// ---------------------------------------------------------------------------
// 5) final: loss = mean( 0.5*(lse_r+lse_c) - scale*diag )
// ---------------------------------------------------------------------------
__global__ void final_kernel(const float* __restrict__ lse, const float* __restrict__ diag,
                             const float* __restrict__ lsp, float* __restrict__ out) {
  const float scale = fminf(expf(lsp[0]), 100.0f);
  float part = 0.f;
  for (int i = threadIdx.x; i < B_N; i += 1024)
    part += 0.5f * (lse[i] + lse[B_N + i]) - scale * diag[i];
  __shared__ float red[1024];
  red[threadIdx.x] = part;
  __syncthreads();
  for (int off = 512; off; off >>= 1) {
    if (threadIdx.x < off) red[threadIdx.x] += red[threadIdx.x + off];
    __syncthreads();
  }
  if (threadIdx.x == 0) {
    float loss = red[0] / (float)B_N;
    out[0] = loss;
    out[1] = loss;
  }
}

extern "C" void kernel_launch(void* const* d_in, const int* in_sizes, int n_in,
                              void* d_out, int out_size, void* d_ws, size_t ws_size,
                              hipStream_t stream) {
  const float* A  = (const float*)d_in[0];  // z_schema
  const float* Bm = (const float*)d_in[1];  // z_seal
  const float* ls = (const float*)d_in[2];  // logit_scale
  float* out = (float*)d_out;

  char* ws = (char*)d_ws;
  unsigned short* Abf = (unsigned short*)ws;                        // 8 MB
  unsigned short* Bbf = Abf + (size_t)B_N * D_K;                    // 8 MB
  float* diagp = (float*)(ws + 2ull * B_N * D_K * 2);               // 64 KB
  float* lsep  = diagp + B_N;                                       // 128 KB
  float* pm    = lsep + 2 * B_N;                                    // 1 MB
  float* ps    = pm + JS * 2 * B_N;                                 // 1 MB

  convert_kernel<<<4096, 256, 0, stream>>>(A, Bm, ls, Abf, Bbf);
  diag_kernel<<<4096, 256, 0, stream>>>(A, Bm, diagp);
  lse_kernel<<<1024, 256, 0, stream>>>(Abf, Bbf, pm, ps);
  combine_kernel<<<128, 256, 0, stream>>>(pm, ps, lsep);
  final_kernel<<<1, 1024, 0, stream>>>(lsep, diagp, ls, out);
}